// Round 1
// baseline (2371.284 us; speedup 1.0000x reference)
//
#include <hip/hip_runtime.h>

#define NN 100000
#define NE 1000000
#define SD 128
#define HID 64

typedef float f4 __attribute__((ext_vector_type(4)));
typedef float f2 __attribute__((ext_vector_type(2)));

__device__ __forceinline__ float silu(float v) {
    return v / (1.0f + __expf(-v));
}

// ---------------- Kernel 1: XA = x @ W1[0:128], XB = x @ W1[128:256] -------------
// wave per 2 nodes, lane = output column (64 outputs)
__global__ __launch_bounds__(256) void k_nodepre(const float* __restrict__ x,
                                                 const float* __restrict__ W1,
                                                 float* __restrict__ XA,
                                                 float* __restrict__ XB) {
    const int wave = (blockIdx.x * 256 + threadIdx.x) >> 6;
    const int lane = threadIdx.x & 63;
    const int n0 = wave * 2;
    if (n0 >= NN) return;
    const float* x0 = x + (size_t)n0 * SD;
    const float* x1 = x + (size_t)(n0 + 1) * SD;
    float a0 = 0.f, b0 = 0.f, a1 = 0.f, b1v = 0.f;
    for (int d4 = 0; d4 < SD / 4; ++d4) {
        f4 xv0 = ((const f4*)x0)[d4];
        f4 xv1 = ((const f4*)x1)[d4];
#pragma unroll
        for (int m = 0; m < 4; ++m) {
            const int d = d4 * 4 + m;
            float wA = W1[d * 64 + lane];
            float wB = W1[(128 + d) * 64 + lane];
            a0 += xv0[m] * wA;  b0 += xv0[m] * wB;
            a1 += xv1[m] * wA;  b1v += xv1[m] * wB;
        }
    }
    XA[(size_t)n0 * 64 + lane] = a0;
    XB[(size_t)n0 * 64 + lane] = b0;
    XA[(size_t)(n0 + 1) * 64 + lane] = a1;
    XB[(size_t)(n0 + 1) * 64 + lane] = b1v;
}

// ---------------- Kernel 2: edge MLP + scatter -----------------------------------
// block = 256 thr = 4 waves; block tile = 64 edges; each wave owns 16 edges.
__global__ __launch_bounds__(256) void k_edge(
    const int* __restrict__ ti, const int* __restrict__ tj, const int* __restrict__ tk,
    const float* __restrict__ attr,
    const float* __restrict__ XA, const float* __restrict__ XB,
    const float* __restrict__ W1, const float* __restrict__ b1,
    const float* __restrict__ W2, const float* __restrict__ b2,
    const float* __restrict__ W3, const float* __restrict__ b3,
    float* __restrict__ sums, float* __restrict__ cnt) {
    __shared__ float H1[4][16][68];   // [wave][edge][dim], pad 4 floats
    __shared__ float H2[4][16][68];
    __shared__ int JL[64];

    const int t = threadIdx.x;
    const int w = t >> 6;
    const int lane = t & 63;
    const int EB = blockIdx.x * 64;

    // ---- phase 1: h1 = silu(XA[i] + XB[k] + attr@W1c + b1) ----
    {
        const int el = t >> 2;   // edge-in-block 0..63  (wave w owns [w*16, w*16+16))
        const int q = t & 3;     // 16-dim chunk
        const int e = EB + el;
        const int i = ti[e];
        const int k = tk[e];
        if (q == 0) {
            const int j = tj[e];
            JL[el] = j;
            atomicAdd(&cnt[j], 1.0f);
        }
        f2 at = ((const f2*)attr)[e];
        const float* xa = XA + (size_t)i * 64 + q * 16;
        const float* xb = XB + (size_t)k * 64 + q * 16;
        const float* c0 = W1 + 256 * 64 + q * 16;
        const float* c1 = W1 + 257 * 64 + q * 16;
        const float* bq = b1 + q * 16;
        float* row = &H1[w][el & 15][q * 16];
#pragma unroll
        for (int m4 = 0; m4 < 4; ++m4) {
            f4 va = ((const f4*)xa)[m4];
            f4 vb = ((const f4*)xb)[m4];
            f4 vc0 = ((const f4*)c0)[m4];
            f4 vc1 = ((const f4*)c1)[m4];
            f4 vbq = ((const f4*)bq)[m4];
            f4 hv;
#pragma unroll
            for (int n = 0; n < 4; ++n) {
                float pre = va[n] + vb[n] + at[0] * vc0[n] + at[1] * vc1[n] + vbq[n];
                hv[n] = silu(pre);
            }
            ((f4*)row)[m4] = hv;
        }
    }
    __syncthreads();

    const int r = lane >> 4;   // row group (4 rows)
    const int c = lane & 15;   // col group (4 cols)

    // ---- phase 2: H2 = silu(H1 @ W2 + b2) ----
    {
        float acc[4][4];
        f4 bini = ((const f4*)b2)[c];
#pragma unroll
        for (int m = 0; m < 4; ++m)
#pragma unroll
            for (int n = 0; n < 4; ++n) acc[m][n] = bini[n];

        const float* H1w = &H1[w][0][0];
#pragma unroll 4
        for (int d = 0; d < 64; ++d) {
            float a0 = H1w[(r * 4 + 0) * 68 + d];
            float a1 = H1w[(r * 4 + 1) * 68 + d];
            float a2 = H1w[(r * 4 + 2) * 68 + d];
            float a3 = H1w[(r * 4 + 3) * 68 + d];
            f4 bv = ((const f4*)(W2 + d * 64))[c];
#pragma unroll
            for (int n = 0; n < 4; ++n) {
                acc[0][n] += a0 * bv[n];
                acc[1][n] += a1 * bv[n];
                acc[2][n] += a2 * bv[n];
                acc[3][n] += a3 * bv[n];
            }
        }
#pragma unroll
        for (int m = 0; m < 4; ++m) {
            f4 hv;
#pragma unroll
            for (int n = 0; n < 4; ++n) hv[n] = silu(acc[m][n]);
            *(f4*)&H2[w][r * 4 + m][c * 4] = hv;
        }
    }
    __syncthreads();

    // ---- phase 3: msgs = H2 @ W3 + b3 ; atomic scatter by j ----
    {
        float acc[4][8];
        f4 b3a = ((const f4*)b3)[c];
        f4 b3b = ((const f4*)b3)[16 + c];
#pragma unroll
        for (int m = 0; m < 4; ++m)
#pragma unroll
            for (int n = 0; n < 4; ++n) {
                acc[m][n] = b3a[n];
                acc[m][4 + n] = b3b[n];
            }

        const float* H2w = &H2[w][0][0];
#pragma unroll 2
        for (int d = 0; d < 64; ++d) {
            float a0 = H2w[(r * 4 + 0) * 68 + d];
            float a1 = H2w[(r * 4 + 1) * 68 + d];
            float a2 = H2w[(r * 4 + 2) * 68 + d];
            float a3 = H2w[(r * 4 + 3) * 68 + d];
            f4 w0 = ((const f4*)(W3 + d * 128))[c];
            f4 w1 = ((const f4*)(W3 + d * 128 + 64))[c];
#pragma unroll
            for (int n = 0; n < 4; ++n) {
                acc[0][n] += a0 * w0[n];  acc[0][4 + n] += a0 * w1[n];
                acc[1][n] += a1 * w0[n];  acc[1][4 + n] += a1 * w1[n];
                acc[2][n] += a2 * w0[n];  acc[2][4 + n] += a2 * w1[n];
                acc[3][n] += a3 * w0[n];  acc[3][4 + n] += a3 * w1[n];
            }
        }
#pragma unroll
        for (int m = 0; m < 4; ++m) {
            const int j = JL[w * 16 + r * 4 + m];
            float* dst = sums + (size_t)j * 128;
#pragma unroll
            for (int n = 0; n < 4; ++n) atomicAdd(dst + c * 4 + n, acc[m][n]);
#pragma unroll
            for (int n = 0; n < 4; ++n) atomicAdd(dst + 64 + c * 4 + n, acc[m][4 + n]);
        }
    }
}

// ---------------- Kernel 3: out = (sums / max(cnt,1)) @ Wout ---------------------
// wave per node, lane handles cols lane and lane+64
__global__ __launch_bounds__(256) void k_out(const float* __restrict__ sums,
                                             const float* __restrict__ cnt,
                                             const float* __restrict__ Wout,
                                             float* __restrict__ out) {
    const int wave = (blockIdx.x * 256 + threadIdx.x) >> 6;
    const int lane = threadIdx.x & 63;
    if (wave >= NN) return;
    const int n = wave;
    const float scale = 1.0f / fmaxf(cnt[n], 1.0f);
    const float* srow = sums + (size_t)n * 128;
    float acc0 = 0.f, acc1 = 0.f;
    for (int d4 = 0; d4 < 32; ++d4) {
        f4 sv = ((const f4*)srow)[d4];
#pragma unroll
        for (int m = 0; m < 4; ++m) {
            const int d = d4 * 4 + m;
            const float av = sv[m] * scale;
            acc0 += av * Wout[d * 128 + lane];
            acc1 += av * Wout[d * 128 + 64 + lane];
        }
    }
    out[(size_t)n * 128 + lane] = acc0;
    out[(size_t)n * 128 + 64 + lane] = acc1;
}

extern "C" void kernel_launch(void* const* d_in, const int* in_sizes, int n_in,
                              void* d_out, int out_size, void* d_ws, size_t ws_size,
                              hipStream_t stream) {
    const float* x    = (const float*)d_in[0];
    const int*   idx  = (const int*)d_in[1];
    const float* attr = (const float*)d_in[2];
    const float* W1   = (const float*)d_in[3];
    const float* b1   = (const float*)d_in[4];
    const float* W2   = (const float*)d_in[5];
    const float* b2   = (const float*)d_in[6];
    const float* W3   = (const float*)d_in[7];
    const float* b3   = (const float*)d_in[8];
    const float* Wout = (const float*)d_in[9];
    float* out = (float*)d_out;

    float* ws   = (float*)d_ws;
    float* XA   = ws;                    // 100000*64
    float* XB   = ws + 6400000;          // 100000*64
    float* sums = ws + 12800000;         // 100000*128
    float* cntv = ws + 25600000;         // 100000
    // zero sums + cnt (contiguous)
    hipMemsetAsync(sums, 0, (size_t)(12800000 + 100000) * sizeof(float), stream);

    hipLaunchKernelGGL(k_nodepre, dim3(12500), dim3(256), 0, stream, x, W1, XA, XB);
    hipLaunchKernelGGL(k_edge, dim3(15625), dim3(256), 0, stream,
                       idx, idx + NE, idx + 2 * NE, attr, XA, XB,
                       W1, b1, W2, b2, W3, b3, sums, cntv);
    hipLaunchKernelGGL(k_out, dim3(25000), dim3(256), 0, stream, sums, cntv, Wout, out);
}

// Round 2
// 847.360 us; speedup vs baseline: 2.7984x; 2.7984x over previous
//
#include <hip/hip_runtime.h>

#define NN 100000
#define NE 1000000
#define SD 128
#define HID 64
#define NBLK_SCAN 391   // ceil(NN/256)

typedef float f4 __attribute__((ext_vector_type(4)));
typedef float f2 __attribute__((ext_vector_type(2)));

__device__ __forceinline__ float silu(float v) {
    return v / (1.0f + __expf(-v));
}

// ws layout (float units)
#define O_SUMS   0            // 12,800,000 f  (NN*128)
#define O_CNT    12800000     // 100,000 i
#define O_OFF    12900000     // 100,001 i
#define O_BSUM   13000064     // 512 i
#define O_BPRE   13000576     // 512 i
#define O_PERM   13001088     // 1,000,000 i
#define O_XA     14001088     // 6,400,000 f
#define O_XB     20401088     // 6,400,000 f  (end 26,801,088 f = 107.2 MB)

// -------- sort: histogram of j --------
__global__ __launch_bounds__(256) void k_hist(const int* __restrict__ tj, int* __restrict__ C) {
    int e = blockIdx.x * 256 + threadIdx.x;
    if (e < NE) atomicAdd(&C[tj[e]], 1);
}

__global__ __launch_bounds__(256) void k_scan1(const int* __restrict__ C, int* __restrict__ Bsum) {
    __shared__ int s[256];
    int t = threadIdx.x;
    int gid = blockIdx.x * 256 + t;
    s[t] = (gid < NN) ? C[gid] : 0;
    __syncthreads();
    for (int off = 128; off > 0; off >>= 1) {
        if (t < off) s[t] += s[t + off];
        __syncthreads();
    }
    if (t == 0) Bsum[blockIdx.x] = s[0];
}

__global__ __launch_bounds__(512) void k_scan2(const int* __restrict__ Bsum, int* __restrict__ Bpre) {
    __shared__ int s[512];
    int t = threadIdx.x;
    int v = (t < NBLK_SCAN) ? Bsum[t] : 0;
    s[t] = v;
    __syncthreads();
    for (int off = 1; off < 512; off <<= 1) {
        int add = (t >= off) ? s[t - off] : 0;
        __syncthreads();
        s[t] += add;
        __syncthreads();
    }
    if (t < NBLK_SCAN) Bpre[t] = s[t] - v;
}

__global__ __launch_bounds__(256) void k_scan3(const int* __restrict__ C, const int* __restrict__ Bpre,
                                               int* __restrict__ offv) {
    __shared__ int s[256];
    int t = threadIdx.x;
    int gid = blockIdx.x * 256 + t;
    int v = (gid < NN) ? C[gid] : 0;
    s[t] = v;
    __syncthreads();
    for (int off = 1; off < 256; off <<= 1) {
        int add = (t >= off) ? s[t - off] : 0;
        __syncthreads();
        s[t] += add;
        __syncthreads();
    }
    if (gid < NN) offv[gid] = Bpre[blockIdx.x] + s[t] - v;
    if (gid == 0) offv[NN] = NE;
}

// scatter: destroys offv (used as cursors)
__global__ __launch_bounds__(256) void k_scatter(const int* __restrict__ tj, int* __restrict__ offv,
                                                 int* __restrict__ perm) {
    int e = blockIdx.x * 256 + threadIdx.x;
    if (e < NE) {
        int j = tj[e];
        int p = atomicAdd(&offv[j], 1);
        perm[p] = e;
    }
}

// -------- node precompute: XA = x@W1a, XB = x@W1b (32 nodes/block) --------
__global__ __launch_bounds__(256) void k_nodepre(const float* __restrict__ x,
                                                 const float* __restrict__ W1,
                                                 float* __restrict__ XA,
                                                 float* __restrict__ XB) {
    __shared__ float X[32][128];
    const int t = threadIdx.x;
    const int n0 = blockIdx.x * 32;
    const f4* xs = (const f4*)(x + (size_t)n0 * 128);
    f4* Xs = (f4*)&X[0][0];
#pragma unroll
    for (int q = 0; q < 4; ++q) Xs[t + 256 * q] = xs[t + 256 * q];
    __syncthreads();
    const int w = t >> 6, lane = t & 63;
    float aA[8], aB[8];
#pragma unroll
    for (int m = 0; m < 8; ++m) { aA[m] = 0.f; aB[m] = 0.f; }
    for (int d = 0; d < 128; ++d) {
        float wA = W1[d * 64 + lane];
        float wB = W1[(128 + d) * 64 + lane];
#pragma unroll
        for (int m = 0; m < 8; ++m) {
            float xv = X[w * 8 + m][d];
            aA[m] += xv * wA;
            aB[m] += xv * wB;
        }
    }
#pragma unroll
    for (int m = 0; m < 8; ++m) {
        XA[(size_t)(n0 + w * 8 + m) * 64 + lane] = aA[m];
        XB[(size_t)(n0 + w * 8 + m) * 64 + lane] = aB[m];
    }
}

// -------- edge MLP on sorted edges + block-compressed atomic scatter --------
__global__ __launch_bounds__(256) void k_edge(
    const int* __restrict__ ti, const int* __restrict__ tj, const int* __restrict__ tk,
    const int* __restrict__ perm, const float* __restrict__ attr,
    const float* __restrict__ XA, const float* __restrict__ XB,
    const float* __restrict__ W1, const float* __restrict__ b1,
    const float* __restrict__ W2, const float* __restrict__ b2,
    const float* __restrict__ W3, const float* __restrict__ b3,
    float* __restrict__ sums) {
    __shared__ float SB[8704];   // H1[4][16][68] | H2[4][16][68]; later M[64] stride 132
    __shared__ int JL[64];
    __shared__ int RS[66];
    __shared__ int nruns_s;

    float* H1 = SB;
    float* H2 = SB + 4352;

    const int t = threadIdx.x;
    const int w = t >> 6;
    const int lane = t & 63;
    const int EB = blockIdx.x * 64;

    // ---- phase 1: h1 = silu(XA[i] + XB[k] + attr@W1c + b1), 4 threads/edge ----
    {
        const int el = t >> 2;
        const int q = t & 3;
        const int e = perm[EB + el];
        const int i = ti[e];
        const int k = tk[e];
        if (q == 0) JL[el] = tj[e];
        f2 at = ((const f2*)attr)[e];
        const float* xa = XA + (size_t)i * 64 + q * 16;
        const float* xb = XB + (size_t)k * 64 + q * 16;
        const float* c0 = W1 + 256 * 64 + q * 16;
        const float* c1 = W1 + 257 * 64 + q * 16;
        const float* bq = b1 + q * 16;
        float* row = H1 + (w * 16 + (el & 15)) * 68 + q * 16;
#pragma unroll
        for (int m4 = 0; m4 < 4; ++m4) {
            f4 va = ((const f4*)xa)[m4];
            f4 vb = ((const f4*)xb)[m4];
            f4 vc0 = ((const f4*)c0)[m4];
            f4 vc1 = ((const f4*)c1)[m4];
            f4 vbq = ((const f4*)bq)[m4];
            f4 hv;
#pragma unroll
            for (int n = 0; n < 4; ++n) {
                float pre = va[n] + vb[n] + at[0] * vc0[n] + at[1] * vc1[n] + vbq[n];
                hv[n] = silu(pre);
            }
            ((f4*)row)[m4] = hv;
        }
    }
    __syncthreads();

    const int r = lane >> 4;   // 4 rows
    const int c = lane & 15;   // 4 cols

    // ---- phase 2: H2 = silu(H1 @ W2 + b2), wave-private slice ----
    {
        float acc[4][4];
        f4 bini = ((const f4*)b2)[c];
#pragma unroll
        for (int m = 0; m < 4; ++m)
#pragma unroll
            for (int n = 0; n < 4; ++n) acc[m][n] = bini[n];

        const float* H1w = H1 + w * 1088;
#pragma unroll 4
        for (int d = 0; d < 64; ++d) {
            float a0 = H1w[(r * 4 + 0) * 68 + d];
            float a1 = H1w[(r * 4 + 1) * 68 + d];
            float a2 = H1w[(r * 4 + 2) * 68 + d];
            float a3 = H1w[(r * 4 + 3) * 68 + d];
            f4 bv = ((const f4*)(W2 + d * 64))[c];
#pragma unroll
            for (int n = 0; n < 4; ++n) {
                acc[0][n] += a0 * bv[n];
                acc[1][n] += a1 * bv[n];
                acc[2][n] += a2 * bv[n];
                acc[3][n] += a3 * bv[n];
            }
        }
        float* H2w = H2 + w * 1088;
#pragma unroll
        for (int m = 0; m < 4; ++m) {
            f4 hv;
#pragma unroll
            for (int n = 0; n < 4; ++n) hv[n] = silu(acc[m][n]);
            *(f4*)&H2w[(r * 4 + m) * 68 + c * 4] = hv;
        }
    }
    __syncthreads();

    // ---- phase 3: msgs = H2 @ W3 + b3 (into registers) ----
    float acc[4][8];
    {
        f4 b3a = ((const f4*)b3)[c];
        f4 b3b = ((const f4*)b3)[16 + c];
#pragma unroll
        for (int m = 0; m < 4; ++m)
#pragma unroll
            for (int n = 0; n < 4; ++n) {
                acc[m][n] = b3a[n];
                acc[m][4 + n] = b3b[n];
            }
        const float* H2w = H2 + w * 1088;
#pragma unroll 2
        for (int d = 0; d < 64; ++d) {
            float a0 = H2w[(r * 4 + 0) * 68 + d];
            float a1 = H2w[(r * 4 + 1) * 68 + d];
            float a2 = H2w[(r * 4 + 2) * 68 + d];
            float a3 = H2w[(r * 4 + 3) * 68 + d];
            f4 w0 = ((const f4*)(W3 + d * 128))[c];
            f4 w1 = ((const f4*)(W3 + d * 128 + 64))[c];
#pragma unroll
            for (int n = 0; n < 4; ++n) {
                acc[0][n] += a0 * w0[n];  acc[0][4 + n] += a0 * w1[n];
                acc[1][n] += a1 * w0[n];  acc[1][4 + n] += a1 * w1[n];
                acc[2][n] += a2 * w0[n];  acc[2][4 + n] += a2 * w1[n];
                acc[3][n] += a3 * w0[n];  acc[3][4 + n] += a3 * w1[n];
            }
        }
    }
    __syncthreads();   // all reads of H1/H2 done; SB reusable as M

    // ---- phase 4: stash msgs to LDS (stride 132 kills write conflicts) ----
    float* M = SB;
#pragma unroll
    for (int m = 0; m < 4; ++m) {
        const int row = w * 16 + r * 4 + m;
        *(f4*)&M[row * 132 + c * 4] = *(f4*)&acc[m][0];
        *(f4*)&M[row * 132 + 64 + c * 4] = *(f4*)&acc[m][4];
    }
    // run heads over sorted JL (wave 0)
    if (t < 64) {
        bool head = (t == 0) || (JL[t] != JL[t - 1]);
        unsigned long long mask = __ballot(head);
        if (head) {
            int rank = __popcll(mask & ((1ull << t) - 1ull));
            RS[rank] = t;
        }
        if (t == 0) {
            int nr = __popcll(mask);
            nruns_s = nr;
            RS[nr] = 64;   // sentinel
        }
    }
    __syncthreads();

    // ---- phase 5: per-run reduce + one atomic row per run ----
    {
        const int col = t & 127;
        const int half = t >> 7;
        const int nr = nruns_s;
        for (int rid = half; rid < nr; rid += 2) {
            const int s0 = RS[rid];
            const int s1 = RS[rid + 1];
            float a = 0.f;
            for (int rr = s0; rr < s1; ++rr) a += M[rr * 132 + col];
            atomicAdd(&sums[(size_t)JL[s0] * 128 + col], a);
        }
    }
}

// -------- out = (sums / max(cnt,1)) @ Wout (32 nodes/block) --------
__global__ __launch_bounds__(256) void k_out(const float* __restrict__ sums,
                                             const int* __restrict__ C,
                                             const float* __restrict__ Wout,
                                             float* __restrict__ out) {
    __shared__ float S[32][128];
    const int t = threadIdx.x;
    const int n0 = blockIdx.x * 32;
    const f4* ss = (const f4*)(sums + (size_t)n0 * 128);
    f4* Ss = (f4*)&S[0][0];
#pragma unroll
    for (int q = 0; q < 4; ++q) {
        const int fidx = t + 256 * q;           // f4 index; row = fidx>>5
        const int row = fidx >> 5;
        const float sc = 1.0f / fmaxf((float)C[n0 + row], 1.0f);
        f4 v = ss[fidx];
#pragma unroll
        for (int n = 0; n < 4; ++n) v[n] *= sc;
        Ss[fidx] = v;
    }
    __syncthreads();
    const int w = t >> 6, lane = t & 63;
    float a0[8], a1[8];
#pragma unroll
    for (int m = 0; m < 8; ++m) { a0[m] = 0.f; a1[m] = 0.f; }
    for (int d = 0; d < 128; ++d) {
        float w0 = Wout[d * 128 + lane];
        float w1 = Wout[d * 128 + 64 + lane];
#pragma unroll
        for (int m = 0; m < 8; ++m) {
            float sv = S[w * 8 + m][d];
            a0[m] += sv * w0;
            a1[m] += sv * w1;
        }
    }
#pragma unroll
    for (int m = 0; m < 8; ++m) {
        out[(size_t)(n0 + w * 8 + m) * 128 + lane] = a0[m];
        out[(size_t)(n0 + w * 8 + m) * 128 + 64 + lane] = a1[m];
    }
}

extern "C" void kernel_launch(void* const* d_in, const int* in_sizes, int n_in,
                              void* d_out, int out_size, void* d_ws, size_t ws_size,
                              hipStream_t stream) {
    const float* x    = (const float*)d_in[0];
    const int*   idx  = (const int*)d_in[1];
    const float* attr = (const float*)d_in[2];
    const float* W1   = (const float*)d_in[3];
    const float* b1   = (const float*)d_in[4];
    const float* W2   = (const float*)d_in[5];
    const float* b2   = (const float*)d_in[6];
    const float* W3   = (const float*)d_in[7];
    const float* b3   = (const float*)d_in[8];
    const float* Wout = (const float*)d_in[9];
    float* out = (float*)d_out;

    const int* ti = idx;
    const int* tj = idx + NE;
    const int* tk = idx + 2 * NE;

    float* ws   = (float*)d_ws;
    float* sums = ws + O_SUMS;
    int*   C    = (int*)(ws + O_CNT);
    int*   offv = (int*)(ws + O_OFF);
    int*   Bsum = (int*)(ws + O_BSUM);
    int*   Bpre = (int*)(ws + O_BPRE);
    int*   perm = (int*)(ws + O_PERM);
    float* XA   = ws + O_XA;
    float* XB   = ws + O_XB;

    // zero sums + counts (contiguous)
    hipMemsetAsync(sums, 0, (size_t)(12800000 + 100000) * sizeof(float), stream);

    hipLaunchKernelGGL(k_nodepre, dim3(3125), dim3(256), 0, stream, x, W1, XA, XB);
    hipLaunchKernelGGL(k_hist,    dim3(3907), dim3(256), 0, stream, tj, C);
    hipLaunchKernelGGL(k_scan1,   dim3(NBLK_SCAN), dim3(256), 0, stream, C, Bsum);
    hipLaunchKernelGGL(k_scan2,   dim3(1), dim3(512), 0, stream, Bsum, Bpre);
    hipLaunchKernelGGL(k_scan3,   dim3(NBLK_SCAN), dim3(256), 0, stream, C, Bpre, offv);
    hipLaunchKernelGGL(k_scatter, dim3(3907), dim3(256), 0, stream, tj, offv, perm);
    hipLaunchKernelGGL(k_edge,    dim3(15625), dim3(256), 0, stream,
                       ti, tj, tk, perm, attr, XA, XB, W1, b1, W2, b2, W3, b3, sums);
    hipLaunchKernelGGL(k_out,     dim3(3125), dim3(256), 0, stream, sums, C, Wout, out);
}

// Round 3
// 548.797 us; speedup vs baseline: 4.3209x; 1.5440x over previous
//
#include <hip/hip_runtime.h>

#define NN 100000
#define NE 1000000
#define SD 128
#define HID 64
#define NBLK_SCAN 391   // ceil(NN/256)

typedef float f4 __attribute__((ext_vector_type(4)));
typedef float f2 __attribute__((ext_vector_type(2)));

__device__ __forceinline__ float silu(float v) {
    return v / (1.0f + __expf(-v));
}

// ws layout (float units)
#define O_SUMS   0            // 6,400,000 f  (NN*64 : segment-sum of H2)
#define O_CNT    6400000      // 100,000 i
#define O_OFF    6500000      // 100,001 i
#define O_BSUM   6600064      // 512 i
#define O_BPRE   6600576      // 512 i
#define O_PERM   6601088      // 1,000,000 i
#define O_XA     7601088      // 6,400,000 f
#define O_XB     14001088     // 6,400,000 f
#define O_W3W    20401088     // 65*128 f (row 64 = b3@Wout)  -> end 20,409,408 f = 81.6 MB

// -------- W3W = W3 @ Wout (rows 0..63), row 64 = b3 @ Wout --------
__global__ __launch_bounds__(128) void k_w3w(const float* __restrict__ W3,
                                             const float* __restrict__ b3,
                                             const float* __restrict__ Wout,
                                             float* __restrict__ W3W) {
    const int row = blockIdx.x;      // 0..64
    const int c = threadIdx.x;       // 0..127
    const float* arow = (row < 64) ? (W3 + row * 128) : b3;
    float acc = 0.f;
    for (int d = 0; d < 128; ++d) acc += arow[d] * Wout[d * 128 + c];
    W3W[row * 128 + c] = acc;
}

// -------- sort: histogram of j --------
__global__ __launch_bounds__(256) void k_hist(const int* __restrict__ tj, int* __restrict__ C) {
    int e = blockIdx.x * 256 + threadIdx.x;
    if (e < NE) atomicAdd(&C[tj[e]], 1);
}

__global__ __launch_bounds__(256) void k_scan1(const int* __restrict__ C, int* __restrict__ Bsum) {
    __shared__ int s[256];
    int t = threadIdx.x;
    int gid = blockIdx.x * 256 + t;
    s[t] = (gid < NN) ? C[gid] : 0;
    __syncthreads();
    for (int off = 128; off > 0; off >>= 1) {
        if (t < off) s[t] += s[t + off];
        __syncthreads();
    }
    if (t == 0) Bsum[blockIdx.x] = s[0];
}

__global__ __launch_bounds__(512) void k_scan2(const int* __restrict__ Bsum, int* __restrict__ Bpre) {
    __shared__ int s[512];
    int t = threadIdx.x;
    int v = (t < NBLK_SCAN) ? Bsum[t] : 0;
    s[t] = v;
    __syncthreads();
    for (int off = 1; off < 512; off <<= 1) {
        int add = (t >= off) ? s[t - off] : 0;
        __syncthreads();
        s[t] += add;
        __syncthreads();
    }
    if (t < NBLK_SCAN) Bpre[t] = s[t] - v;
}

__global__ __launch_bounds__(256) void k_scan3(const int* __restrict__ C, const int* __restrict__ Bpre,
                                               int* __restrict__ offv) {
    __shared__ int s[256];
    int t = threadIdx.x;
    int gid = blockIdx.x * 256 + t;
    int v = (gid < NN) ? C[gid] : 0;
    s[t] = v;
    __syncthreads();
    for (int off = 1; off < 256; off <<= 1) {
        int add = (t >= off) ? s[t - off] : 0;
        __syncthreads();
        s[t] += add;
        __syncthreads();
    }
    if (gid < NN) offv[gid] = Bpre[blockIdx.x] + s[t] - v;
    if (gid == 0) offv[NN] = NE;
}

// scatter: destroys offv (used as cursors)
__global__ __launch_bounds__(256) void k_scatter(const int* __restrict__ tj, int* __restrict__ offv,
                                                 int* __restrict__ perm) {
    int e = blockIdx.x * 256 + threadIdx.x;
    if (e < NE) {
        int j = tj[e];
        int p = atomicAdd(&offv[j], 1);
        perm[p] = e;
    }
}

// -------- node precompute: XA = x@W1a, XB = x@W1b (32 nodes/block) --------
__global__ __launch_bounds__(256) void k_nodepre(const float* __restrict__ x,
                                                 const float* __restrict__ W1,
                                                 float* __restrict__ XA,
                                                 float* __restrict__ XB) {
    __shared__ float X[32][128];
    const int t = threadIdx.x;
    const int n0 = blockIdx.x * 32;
    const f4* xs = (const f4*)(x + (size_t)n0 * 128);
    f4* Xs = (f4*)&X[0][0];
#pragma unroll
    for (int q = 0; q < 4; ++q) Xs[t + 256 * q] = xs[t + 256 * q];
    __syncthreads();
    const int w = t >> 6, lane = t & 63;
    float aA[8], aB[8];
#pragma unroll
    for (int m = 0; m < 8; ++m) { aA[m] = 0.f; aB[m] = 0.f; }
    for (int d = 0; d < 128; ++d) {
        float wA = W1[d * 64 + lane];
        float wB = W1[(128 + d) * 64 + lane];
#pragma unroll
        for (int m = 0; m < 8; ++m) {
            float xv = X[w * 8 + m][d];
            aA[m] += xv * wA;
            aB[m] += xv * wB;
        }
    }
#pragma unroll
    for (int m = 0; m < 8; ++m) {
        XA[(size_t)(n0 + w * 8 + m) * 64 + lane] = aA[m];
        XB[(size_t)(n0 + w * 8 + m) * 64 + lane] = aB[m];
    }
}

// -------- edge kernel: h1 -> h2, segment-reduce H2 by j, atomic scatter --------
// block = 256 thr = 4 waves; 64 edges/block; wave owns 16 edges through phase 2.
__global__ __launch_bounds__(256, 8) void k_edge(
    const int* __restrict__ ti, const int* __restrict__ tj, const int* __restrict__ tk,
    const int* __restrict__ perm, const float* __restrict__ attr,
    const float* __restrict__ XA, const float* __restrict__ XB,
    const float* __restrict__ W1, const float* __restrict__ b1,
    const float* __restrict__ W2, const float* __restrict__ b2,
    float* __restrict__ sums) {
    __shared__ float SB[64 * 68];  // H1[64][68], then reused as H2/M[64][68]
    __shared__ int JL[64];
    __shared__ int RS[66];
    __shared__ int nruns_s;

    const int t = threadIdx.x;
    const int w = t >> 6;
    const int lane = t & 63;
    const int EB = blockIdx.x * 64;

    // ---- phase 1: h1 = silu(XA[i] + XB[k] + attr@W1c + b1), 4 threads/edge ----
    {
        const int el = t >> 2;
        const int q = t & 3;
        const int e = perm[EB + el];
        const int i = ti[e];
        const int k = tk[e];
        if (q == 0) JL[el] = tj[e];
        f2 at = ((const f2*)attr)[e];
        const float* xa = XA + (size_t)i * 64 + q * 16;
        const float* xb = XB + (size_t)k * 64 + q * 16;
        const float* c0 = W1 + 256 * 64 + q * 16;
        const float* c1 = W1 + 257 * 64 + q * 16;
        const float* bq = b1 + q * 16;
        float* row = SB + el * 68 + q * 16;
#pragma unroll
        for (int m4 = 0; m4 < 4; ++m4) {
            f4 va = ((const f4*)xa)[m4];
            f4 vb = ((const f4*)xb)[m4];
            f4 vc0 = ((const f4*)c0)[m4];
            f4 vc1 = ((const f4*)c1)[m4];
            f4 vbq = ((const f4*)bq)[m4];
            f4 hv;
#pragma unroll
            for (int n = 0; n < 4; ++n) {
                float pre = va[n] + vb[n] + at[0] * vc0[n] + at[1] * vc1[n] + vbq[n];
                hv[n] = silu(pre);
            }
            ((f4*)row)[m4] = hv;
        }
    }
    __syncthreads();

    const int r = lane >> 4;   // 4 row-groups of 4
    const int c = lane & 15;   // 16 col-groups of 4

    // ---- phase 2: H2 = silu(H1 @ W2 + b2) into registers (wave-private slice) ----
    float acc[4][4];
    {
        f4 bini = ((const f4*)b2)[c];
#pragma unroll
        for (int m = 0; m < 4; ++m)
#pragma unroll
            for (int n = 0; n < 4; ++n) acc[m][n] = bini[n];

        const float* H1w = SB + w * 16 * 68;
#pragma unroll 4
        for (int d = 0; d < 64; ++d) {
            float a0 = H1w[(r * 4 + 0) * 68 + d];
            float a1 = H1w[(r * 4 + 1) * 68 + d];
            float a2 = H1w[(r * 4 + 2) * 68 + d];
            float a3 = H1w[(r * 4 + 3) * 68 + d];
            f4 bv = ((const f4*)(W2 + d * 64))[c];
#pragma unroll
            for (int n = 0; n < 4; ++n) {
                acc[0][n] += a0 * bv[n];
                acc[1][n] += a1 * bv[n];
                acc[2][n] += a2 * bv[n];
                acc[3][n] += a3 * bv[n];
            }
        }
    }
    __syncthreads();   // all H1 reads done; SB reusable as M

    // ---- phase 3: write silu(acc) to M; wave 0 finds run heads over sorted JL ----
    float* M = SB;
#pragma unroll
    for (int m = 0; m < 4; ++m) {
        const int row = w * 16 + r * 4 + m;
        f4 hv;
#pragma unroll
        for (int n = 0; n < 4; ++n) hv[n] = silu(acc[m][n]);
        *(f4*)&M[row * 68 + c * 4] = hv;
    }
    if (t < 64) {
        bool head = (t == 0) || (JL[t] != JL[t - 1]);
        unsigned long long mask = __ballot(head);
        if (head) {
            int rank = __popcll(mask & ((1ull << t) - 1ull));
            RS[rank] = t;
        }
        if (t == 0) {
            int nr = __popcll(mask);
            nruns_s = nr;
            RS[nr] = 64;   // sentinel
        }
    }
    __syncthreads();

    // ---- phase 4: per-run column reduce + one 64-wide atomic row per run ----
    {
        const int col = t & 63;
        const int q = t >> 6;
        const int nr = nruns_s;
        for (int rid = q; rid < nr; rid += 4) {
            const int s0 = RS[rid];
            const int s1 = RS[rid + 1];
            float a = 0.f;
            for (int rr = s0; rr < s1; ++rr) a += M[rr * 68 + col];
            atomicAdd(&sums[(size_t)JL[s0] * 64 + col], a);
        }
    }
}

// -------- out = (sums/max(cnt,1)) @ W3W + [cnt>0]*bout (32 nodes/block) --------
__global__ __launch_bounds__(256) void k_out(const float* __restrict__ sums,
                                             const int* __restrict__ C,
                                             const float* __restrict__ W3W,
                                             float* __restrict__ out) {
    __shared__ float S[32][64];
    __shared__ float bs[32];
    const int t = threadIdx.x;
    const int n0 = blockIdx.x * 32;
    const f4* ss = (const f4*)(sums + (size_t)n0 * 64);
    f4* Ss = (f4*)&S[0][0];
#pragma unroll
    for (int q = 0; q < 2; ++q) {
        const int fidx = t + 256 * q;       // 512 f4 total; 16 f4 per row
        const int row = fidx >> 4;
        const int cn = C[n0 + row];
        const float sc = (cn > 0) ? 1.0f / (float)cn : 0.0f;
        f4 v = ss[fidx];
#pragma unroll
        for (int n = 0; n < 4; ++n) v[n] *= sc;
        Ss[fidx] = v;
    }
    if (t < 32) bs[t] = (C[n0 + t] > 0) ? 1.0f : 0.0f;
    __syncthreads();
    const int w = t >> 6, lane = t & 63;
    const float* bout = W3W + 64 * 128;
    float a0[8], a1[8];
#pragma unroll
    for (int m = 0; m < 8; ++m) { a0[m] = 0.f; a1[m] = 0.f; }
    for (int d = 0; d < 64; ++d) {
        float w0 = W3W[d * 128 + lane];
        float w1 = W3W[d * 128 + 64 + lane];
#pragma unroll
        for (int m = 0; m < 8; ++m) {
            float sv = S[w * 8 + m][d];
            a0[m] += sv * w0;
            a1[m] += sv * w1;
        }
    }
    const float bo0 = bout[lane], bo1 = bout[64 + lane];
#pragma unroll
    for (int m = 0; m < 8; ++m) {
        const int node = n0 + w * 8 + m;
        const float b = bs[w * 8 + m];
        out[(size_t)node * 128 + lane] = a0[m] + b * bo0;
        out[(size_t)node * 128 + 64 + lane] = a1[m] + b * bo1;
    }
}

extern "C" void kernel_launch(void* const* d_in, const int* in_sizes, int n_in,
                              void* d_out, int out_size, void* d_ws, size_t ws_size,
                              hipStream_t stream) {
    const float* x    = (const float*)d_in[0];
    const int*   idx  = (const int*)d_in[1];
    const float* attr = (const float*)d_in[2];
    const float* W1   = (const float*)d_in[3];
    const float* b1   = (const float*)d_in[4];
    const float* W2   = (const float*)d_in[5];
    const float* b2   = (const float*)d_in[6];
    const float* W3   = (const float*)d_in[7];
    const float* b3   = (const float*)d_in[8];
    const float* Wout = (const float*)d_in[9];
    float* out = (float*)d_out;

    const int* ti = idx;
    const int* tj = idx + NE;
    const int* tk = idx + 2 * NE;

    float* ws   = (float*)d_ws;
    float* sums = ws + O_SUMS;
    int*   C    = (int*)(ws + O_CNT);
    int*   offv = (int*)(ws + O_OFF);
    int*   Bsum = (int*)(ws + O_BSUM);
    int*   Bpre = (int*)(ws + O_BPRE);
    int*   perm = (int*)(ws + O_PERM);
    float* XA   = ws + O_XA;
    float* XB   = ws + O_XB;
    float* W3W  = ws + O_W3W;

    // zero sums + counts (contiguous)
    hipMemsetAsync(sums, 0, (size_t)(6400000 + 100000) * sizeof(float), stream);

    hipLaunchKernelGGL(k_w3w,     dim3(65), dim3(128), 0, stream, W3, b3, Wout, W3W);
    hipLaunchKernelGGL(k_nodepre, dim3(3125), dim3(256), 0, stream, x, W1, XA, XB);
    hipLaunchKernelGGL(k_hist,    dim3(3907), dim3(256), 0, stream, tj, C);
    hipLaunchKernelGGL(k_scan1,   dim3(NBLK_SCAN), dim3(256), 0, stream, C, Bsum);
    hipLaunchKernelGGL(k_scan2,   dim3(1), dim3(512), 0, stream, Bsum, Bpre);
    hipLaunchKernelGGL(k_scan3,   dim3(NBLK_SCAN), dim3(256), 0, stream, C, Bpre, offv);
    hipLaunchKernelGGL(k_scatter, dim3(3907), dim3(256), 0, stream, tj, offv, perm);
    hipLaunchKernelGGL(k_edge,    dim3(15625), dim3(256), 0, stream,
                       ti, tj, tk, perm, attr, XA, XB, W1, b1, W2, b2, sums);
    hipLaunchKernelGGL(k_out,     dim3(3125), dim3(256), 0, stream, sums, C, W3W, out);
}

// Round 5
// 440.577 us; speedup vs baseline: 5.3822x; 1.2456x over previous
//
#include <hip/hip_runtime.h>

#define NN 100000
#define NE 1000000
#define NBLK_SCAN 391   // ceil(NN/256)

typedef float f4 __attribute__((ext_vector_type(4)));
typedef float f2 __attribute__((ext_vector_type(2)));
typedef _Float16 h8 __attribute__((ext_vector_type(8)));

__device__ __forceinline__ float silu(float v) {
    return v / (1.0f + __expf(-v));
}

// ws layout (float units)
#define O_SUMS   0            // 6,400,000 f  (NN*64 : segment-sum of H2)
#define O_CNT    6400000      // 100,000 i
#define O_OFF    6500000      // 100,000 i
#define O_BSUM   6600000      // 512 i
#define O_BPRE   6600512      // 512 i
#define O_PERM   6601024      // 1,000,000 i
#define O_XA     7601024      // 3,200,000 f (= 6.4M fp16)
#define O_XB     10801024     // 3,200,000 f
#define O_W3W    14001024     // 65*128 f (row 64 = b3@Wout)
#define O_W2T    14009344     // 2048 f (= 64*64 fp16, W2 transposed)

#define NODEPRE_B 3125
#define HIST_B    3907
#define W3W_B     33
#define PREP_B    (NODEPRE_B + HIST_B + W3W_B + 1)   // 7066

// ==== fused prep: nodepre | histogram | W3W=W3@Wout | W2^T fp16 ====
__global__ __launch_bounds__(256) void k_prep(
    const float* __restrict__ x, const int* __restrict__ tj,
    const float* __restrict__ W1, const float* __restrict__ W2,
    const float* __restrict__ W3, const float* __restrict__ b3,
    const float* __restrict__ Wout,
    _Float16* __restrict__ XA, _Float16* __restrict__ XB,
    int* __restrict__ C, float* __restrict__ W3W, _Float16* __restrict__ W2t) {
    __shared__ float X[32][128];
    const int b = blockIdx.x;
    const int t = threadIdx.x;
    if (b < NODEPRE_B) {
        // ---- XA = x@W1a, XB = x@W1b, stored fp16 (32 nodes/block) ----
        const int n0 = b * 32;
        const f4* xs = (const f4*)(x + (size_t)n0 * 128);
        f4* Xs = (f4*)&X[0][0];
#pragma unroll
        for (int q = 0; q < 4; ++q) Xs[t + 256 * q] = xs[t + 256 * q];
        __syncthreads();
        const int w = t >> 6, lane = t & 63;
        float aA[8], aB[8];
#pragma unroll
        for (int m = 0; m < 8; ++m) { aA[m] = 0.f; aB[m] = 0.f; }
        for (int d = 0; d < 128; ++d) {
            float wA = W1[d * 64 + lane];
            float wB = W1[(128 + d) * 64 + lane];
#pragma unroll
            for (int m = 0; m < 8; ++m) {
                float xv = X[w * 8 + m][d];
                aA[m] += xv * wA;
                aB[m] += xv * wB;
            }
        }
#pragma unroll
        for (int m = 0; m < 8; ++m) {
            XA[(size_t)(n0 + w * 8 + m) * 64 + lane] = (_Float16)aA[m];
            XB[(size_t)(n0 + w * 8 + m) * 64 + lane] = (_Float16)aB[m];
        }
    } else if (b < NODEPRE_B + HIST_B) {
        int e = (b - NODEPRE_B) * 256 + t;
        if (e < NE) atomicAdd(&C[tj[e]], 1);
    } else if (b < NODEPRE_B + HIST_B + W3W_B) {
        // ---- W3W rows (2 per block); row 64 = b3@Wout ----
        const int row = (b - NODEPRE_B - HIST_B) * 2 + (t >> 7);
        const int c = t & 127;
        if (row < 65) {
            const float* arow = (row < 64) ? (W3 + row * 128) : b3;
            float acc = 0.f;
            for (int d = 0; d < 128; ++d) acc += arow[d] * Wout[d * 128 + c];
            W3W[row * 128 + c] = acc;
        }
    } else {
        // ---- W2t[n][k] = W2[k][n] fp16 ----
#pragma unroll
        for (int u = 0; u < 16; ++u) {
            const int idx = t * 16 + u;
            const int n = idx >> 6, k = idx & 63;
            W2t[idx] = (_Float16)W2[k * 64 + n];
        }
    }
}

// ==== scan stage 1: block-local exclusive scan of counts ====
__global__ __launch_bounds__(256) void k_scan_local(const int* __restrict__ C,
                                                    int* __restrict__ offv,
                                                    int* __restrict__ Bsum) {
    __shared__ int s[256];
    const int t = threadIdx.x;
    const int gid = blockIdx.x * 256 + t;
    const int v = (gid < NN) ? C[gid] : 0;
    s[t] = v;
    __syncthreads();
    for (int off = 1; off < 256; off <<= 1) {
        int add = (t >= off) ? s[t - off] : 0;
        __syncthreads();
        s[t] += add;
        __syncthreads();
    }
    if (gid < NN) offv[gid] = s[t] - v;
    if (t == 255) Bsum[blockIdx.x] = s[255];
}

// ==== scan stage 2: exclusive scan of 391 block sums ====
__global__ __launch_bounds__(512) void k_scan_block(const int* __restrict__ Bsum,
                                                    int* __restrict__ Bpre) {
    __shared__ int s[512];
    const int t = threadIdx.x;
    const int v = (t < NBLK_SCAN) ? Bsum[t] : 0;
    s[t] = v;
    __syncthreads();
    for (int off = 1; off < 512; off <<= 1) {
        int add = (t >= off) ? s[t - off] : 0;
        __syncthreads();
        s[t] += add;
        __syncthreads();
    }
    if (t < NBLK_SCAN) Bpre[t] = s[t] - v;
}

// ==== scatter: perm[pos] = e, pos = global offset of e within its j-group ====
__global__ __launch_bounds__(256) void k_scatter(const int* __restrict__ tj,
                                                 const int* __restrict__ Bpre,
                                                 int* __restrict__ offv,
                                                 int* __restrict__ perm) {
    int e = blockIdx.x * 256 + threadIdx.x;
    if (e < NE) {
        int j = tj[e];
        int p = Bpre[j >> 8] + atomicAdd(&offv[j], 1);
        perm[p] = e;
    }
}

// ==== edge kernel: h1 (VALU) -> h2 (MFMA fp16) -> segment-reduce by j ====
// block = 256 = 4 waves; 64 edges/block; wave owns 16 edges.
__global__ __launch_bounds__(256, 8) void k_edge(
    const int* __restrict__ ti, const int* __restrict__ tj, const int* __restrict__ tk,
    const int* __restrict__ perm, const float* __restrict__ attr,
    const _Float16* __restrict__ XA, const _Float16* __restrict__ XB,
    const float* __restrict__ W1, const float* __restrict__ b1,
    const _Float16* __restrict__ W2t, const float* __restrict__ b2,
    float* __restrict__ sums) {
    __shared__ __align__(16) char SBraw[64 * 68 * 4];  // M[64][68] f32; H1h[64][72] fp16 fits
    __shared__ int JL[64];
    __shared__ int RS[66];
    __shared__ int nruns_s;

    _Float16* H1h = (_Float16*)SBraw;   // [64][72]
    float* M = (float*)SBraw;           // [64][68]

    const int t = threadIdx.x;
    const int w = t >> 6;
    const int lane = t & 63;
    const int EB = blockIdx.x * 64;

    // ---- phase 1: h1 = silu(XA[i] + XB[k] + attr@W1c + b1) fp16, 4 thr/edge ----
    {
        const int el = t >> 2;
        const int q = t & 3;
        const int e = perm[EB + el];
        const int i = ti[e];
        const int k = tk[e];
        if (q == 0) JL[el] = tj[e];
        f2 at = ((const f2*)attr)[e];
        const _Float16* xa = XA + (size_t)i * 64 + q * 16;
        const _Float16* xb = XB + (size_t)k * 64 + q * 16;
        h8 va0 = ((const h8*)xa)[0], va1 = ((const h8*)xa)[1];
        h8 vb0 = ((const h8*)xb)[0], vb1 = ((const h8*)xb)[1];
        float fa[16], fb[16];
#pragma unroll
        for (int n = 0; n < 8; ++n) {
            fa[n] = (float)va0[n]; fa[8 + n] = (float)va1[n];
            fb[n] = (float)vb0[n]; fb[8 + n] = (float)vb1[n];
        }
        const float* c0 = W1 + 256 * 64 + q * 16;
        const float* c1 = W1 + 257 * 64 + q * 16;
        const float* bq = b1 + q * 16;
        _Float16 hrow[16];
#pragma unroll
        for (int m4 = 0; m4 < 4; ++m4) {
            f4 vc0 = ((const f4*)c0)[m4];
            f4 vc1 = ((const f4*)c1)[m4];
            f4 vbq = ((const f4*)bq)[m4];
#pragma unroll
            for (int n = 0; n < 4; ++n) {
                const int idx = m4 * 4 + n;
                float pre = fa[idx] + fb[idx] + at[0] * vc0[n] + at[1] * vc1[n] + vbq[n];
                hrow[idx] = (_Float16)silu(pre);
            }
        }
        h8 s0, s1;
#pragma unroll
        for (int n = 0; n < 8; ++n) { s0[n] = hrow[n]; s1[n] = hrow[8 + n]; }
        _Float16* row = H1h + el * 72 + q * 16;
        ((h8*)row)[0] = s0;
        ((h8*)row)[1] = s1;
    }
    __syncthreads();

    // ---- phase 2: H2 = silu(H1 @ W2 + b2) via mfma_f32_16x16x32_f16 ----
    const int r15 = lane & 15;
    const int blk = lane >> 4;
    float h2v[16];
    {
        const _Float16* H1w = H1h + (w * 16) * 72;
        h8 a0 = *(const h8*)(H1w + r15 * 72 + blk * 8);        // k = 0..31 slice
        h8 a1 = *(const h8*)(H1w + r15 * 72 + 32 + blk * 8);   // k = 32..63 slice
#pragma unroll
        for (int ncol = 0; ncol < 4; ++ncol) {
            const _Float16* Wn = W2t + (ncol * 16 + r15) * 64 + blk * 8;
            h8 b0 = *(const h8*)(Wn);
            h8 b1v = *(const h8*)(Wn + 32);
            const float bc = b2[ncol * 16 + r15];
            f4 acc = {bc, bc, bc, bc};
            acc = __builtin_amdgcn_mfma_f32_16x16x32_f16(a0, b0, acc, 0, 0, 0);
            acc = __builtin_amdgcn_mfma_f32_16x16x32_f16(a1, b1v, acc, 0, 0, 0);
#pragma unroll
            for (int reg = 0; reg < 4; ++reg) h2v[ncol * 4 + reg] = silu(acc[reg]);
        }
    }
    __syncthreads();   // all H1 reads done; SBraw reusable as M

    // ---- phase 3: write H2 to M (f32); wave 0 finds run heads over sorted JL ----
#pragma unroll
    for (int ncol = 0; ncol < 4; ++ncol)
#pragma unroll
        for (int reg = 0; reg < 4; ++reg)
            M[(w * 16 + blk * 4 + reg) * 68 + ncol * 16 + r15] = h2v[ncol * 4 + reg];
    if (t < 64) {
        bool head = (t == 0) || (JL[t] != JL[t - 1]);
        unsigned long long mask = __ballot(head);
        if (head) {
            int rank = __popcll(mask & ((1ull << t) - 1ull));
            RS[rank] = t;
        }
        if (t == 0) {
            int nr = __popcll(mask);
            nruns_s = nr;
            RS[nr] = 64;   // sentinel
        }
    }
    __syncthreads();

    // ---- phase 4: per-run column reduce + one 64-wide atomic row per run ----
    {
        const int col = t & 63;
        const int q4 = t >> 6;
        const int nr = nruns_s;
        for (int rid = q4; rid < nr; rid += 4) {
            const int s0 = RS[rid];
            const int s1 = RS[rid + 1];
            float a = 0.f;
            for (int rr = s0; rr < s1; ++rr) a += M[rr * 68 + col];
            atomicAdd(&sums[(size_t)JL[s0] * 64 + col], a);
        }
    }
}

// ==== out = (sums/max(cnt,1)) @ W3W + [cnt>0]*bout (32 nodes/block) ====
__global__ __launch_bounds__(256) void k_out(const float* __restrict__ sums,
                                             const int* __restrict__ C,
                                             const float* __restrict__ W3W,
                                             float* __restrict__ out) {
    __shared__ float S[32][64];
    __shared__ float bs[32];
    const int t = threadIdx.x;
    const int n0 = blockIdx.x * 32;
    const f4* ss = (const f4*)(sums + (size_t)n0 * 64);
    f4* Ss = (f4*)&S[0][0];
#pragma unroll
    for (int q = 0; q < 2; ++q) {
        const int fidx = t + 256 * q;       // 512 f4 total; 16 f4 per row
        const int row = fidx >> 4;
        const int cn = C[n0 + row];
        const float sc = (cn > 0) ? 1.0f / (float)cn : 0.0f;
        f4 v = ss[fidx];
#pragma unroll
        for (int n = 0; n < 4; ++n) v[n] *= sc;
        Ss[fidx] = v;
    }
    if (t < 32) bs[t] = (C[n0 + t] > 0) ? 1.0f : 0.0f;
    __syncthreads();
    const int w = t >> 6, lane = t & 63;
    const float* bout = W3W + 64 * 128;
    float a0[8], a1[8];
#pragma unroll
    for (int m = 0; m < 8; ++m) { a0[m] = 0.f; a1[m] = 0.f; }
    for (int d = 0; d < 64; ++d) {
        float w0 = W3W[d * 128 + lane];
        float w1 = W3W[d * 128 + 64 + lane];
#pragma unroll
        for (int m = 0; m < 8; ++m) {
            float sv = S[w * 8 + m][d];
            a0[m] += sv * w0;
            a1[m] += sv * w1;
        }
    }
    const float bo0 = bout[lane], bo1 = bout[64 + lane];
#pragma unroll
    for (int m = 0; m < 8; ++m) {
        const int node = n0 + w * 8 + m;
        const float b = bs[w * 8 + m];
        out[(size_t)node * 128 + lane] = a0[m] + b * bo0;
        out[(size_t)node * 128 + 64 + lane] = a1[m] + b * bo1;
    }
}

extern "C" void kernel_launch(void* const* d_in, const int* in_sizes, int n_in,
                              void* d_out, int out_size, void* d_ws, size_t ws_size,
                              hipStream_t stream) {
    const float* x    = (const float*)d_in[0];
    const int*   idx  = (const int*)d_in[1];
    const float* attr = (const float*)d_in[2];
    const float* W1   = (const float*)d_in[3];
    const float* b1   = (const float*)d_in[4];
    const float* W2   = (const float*)d_in[5];
    const float* b2   = (const float*)d_in[6];
    const float* W3   = (const float*)d_in[7];
    const float* b3   = (const float*)d_in[8];
    const float* Wout = (const float*)d_in[9];
    float* out = (float*)d_out;

    const int* ti = idx;
    const int* tj = idx + NE;
    const int* tk = idx + 2 * NE;

    float* ws   = (float*)d_ws;
    float* sums = ws + O_SUMS;
    int*   C    = (int*)(ws + O_CNT);
    int*   offv = (int*)(ws + O_OFF);
    int*   Bsum = (int*)(ws + O_BSUM);
    int*   Bpre = (int*)(ws + O_BPRE);
    int*   perm = (int*)(ws + O_PERM);
    _Float16* XA  = (_Float16*)(ws + O_XA);
    _Float16* XB  = (_Float16*)(ws + O_XB);
    float* W3W  = ws + O_W3W;
    _Float16* W2t = (_Float16*)(ws + O_W2T);

    // zero sums + counts (contiguous)
    hipMemsetAsync(sums, 0, (size_t)(6400000 + 100000) * sizeof(float), stream);

    hipLaunchKernelGGL(k_prep,       dim3(PREP_B), dim3(256), 0, stream,
                       x, tj, W1, W2, W3, b3, Wout, XA, XB, C, W3W, W2t);
    hipLaunchKernelGGL(k_scan_local, dim3(NBLK_SCAN), dim3(256), 0, stream, C, offv, Bsum);
    hipLaunchKernelGGL(k_scan_block, dim3(1), dim3(512), 0, stream, Bsum, Bpre);
    hipLaunchKernelGGL(k_scatter,    dim3(3907), dim3(256), 0, stream, tj, Bpre, offv, perm);
    hipLaunchKernelGGL(k_edge,       dim3(15625), dim3(256), 0, stream,
                       ti, tj, tk, perm, attr, XA, XB, W1, b1, W2t, b2, sums);
    hipLaunchKernelGGL(k_out,        dim3(3125), dim3(256), 0, stream, sums, C, W3W, out);
}